// Round 1
// baseline (491.795 us; speedup 1.0000x reference)
//
#include <hip/hip_runtime.h>
#include <math.h>

#define B 128
#define L 196
#define DTOP 64
#define DLVL 128
#define K 512
#define NCLS 15

// d_out layout (floats)
#define DIFF_OFF 12845056        // 4*B*L*128
#define ID_OFF   12845057
#define OT_OFF   12945409        // ID_OFF + 4*B*L
// ws layout (floats)
#define WS_Q4    0
#define WS_N2TOP (B*L*DTOP)                  // 1,605,632
#define WS_N2LVL (WS_N2TOP + NCLS*K)         // + 7,680
#define WS_INVE  (WS_N2LVL + 4*NCLS*K)       // + 30,720

__global__ __launch_bounds__(256) void precompute_norms(
    const float* __restrict__ cb_top, const float* __restrict__ cb_lvl, float* __restrict__ ws)
{
    int id = blockIdx.x * 256 + threadIdx.x;
    float* n2top = ws + WS_N2TOP;
    float* n2lvl = ws + WS_N2LVL;
    float* inve  = ws + WS_INVE;
    if (id < NCLS * K) {
        int c = id / K, k = id % K;
        float s = 0.f;
        for (int dd = 0; dd < DTOP; ++dd) {
            float v = cb_top[(size_t)(c * DTOP + dd) * K + k];
            s = fmaf(v, v, s);
        }
        n2top[id] = s;
    } else if (id < NCLS * K + 4 * NCLS * K) {
        int id2 = id - NCLS * K;
        int j = id2 / (NCLS * K);
        int r = id2 % (NCLS * K);
        int c = r / K, k = r % K;
        float s = 0.f;
        for (int dd = 0; dd < DLVL; ++dd) {
            float v = cb_lvl[((size_t)(j * NCLS + c) * DLVL + dd) * K + k];
            s = fmaf(v, v, s);
        }
        n2lvl[id2] = s;
        if (j == 0) inve[r] = 1.f / (sqrtf(s) + 1e-8f);
    }
}

// Top level: d=64, codebook cb_top[label[b]] (64 x 512). Writes q4 to ws, adds to diff.
__global__ __launch_bounds__(256) void vq_top(
    const float* __restrict__ input, const float* __restrict__ cb_top,
    const int* __restrict__ label, const float* __restrict__ n2top,
    float* __restrict__ q4, float* __restrict__ diff_out)
{
    __shared__ float xT[DTOP][64];     // 16 KB
    __shared__ float Ec[DTOP][128];    // 32 KB
    __shared__ float n2c[128];
    __shared__ float runv[64];
    __shared__ int   runi[64];
    __shared__ float xnorm2[64];

    const int tid = threadIdx.x;
    const int tile = blockIdx.x;
    const int b = blockIdx.y;
    const int t0 = tile * 64;
    const int c = label[b];
    const float* Eb = cb_top + (size_t)c * DTOP * K;
    const float* n2 = n2top + (size_t)c * K;

    // stage x transposed: 64 tokens x 16 float4
    for (int it = 0; it < 4; ++it) {
        int idx = it * 256 + tid;
        int tok = idx >> 4;
        int sg = idx & 15;
        int l = t0 + tok;
        float4 v = make_float4(0.f, 0.f, 0.f, 0.f);
        if (l < L)
            v = *reinterpret_cast<const float4*>(input + ((size_t)(4 * B + b) * L + l) * DTOP + sg * 4);
        xT[sg * 4 + 0][tok] = v.x; xT[sg * 4 + 1][tok] = v.y;
        xT[sg * 4 + 2][tok] = v.z; xT[sg * 4 + 3][tok] = v.w;
    }
    __syncthreads();
    if (tid < 64) {
        float s = 0.f;
        for (int dd = 0; dd < DTOP; ++dd) { float v = xT[dd][tid]; s = fmaf(v, v, s); }
        xnorm2[tid] = s;
        runv[tid] = __builtin_inff();
        runi[tid] = 0;
    }
    const int cg = tid & 31, tg = tid >> 5;

    for (int cc = 0; cc < 4; ++cc) {
        __syncthreads();
        for (int it = 0; it < 8; ++it) {
            int idx = it * 256 + tid;
            int row = idx >> 5;
            int c4 = idx & 31;
            *reinterpret_cast<float4*>(&Ec[row][c4 * 4]) =
                *reinterpret_cast<const float4*>(Eb + (size_t)row * K + cc * 128 + c4 * 4);
        }
        if (tid < 32)
            *reinterpret_cast<float4*>(&n2c[tid * 4]) =
                *reinterpret_cast<const float4*>(n2 + cc * 128 + tid * 4);
        __syncthreads();

        float acc[8][4];
        #pragma unroll
        for (int i = 0; i < 8; ++i)
            #pragma unroll
            for (int j2 = 0; j2 < 4; ++j2) acc[i][j2] = 0.f;

        for (int dd = 0; dd < DTOP; ++dd) {
            float4 xa = *reinterpret_cast<const float4*>(&xT[dd][tg * 8]);
            float4 xb = *reinterpret_cast<const float4*>(&xT[dd][tg * 8 + 4]);
            float4 ev = *reinterpret_cast<const float4*>(&Ec[dd][cg * 4]);
            float xs[8] = {xa.x, xa.y, xa.z, xa.w, xb.x, xb.y, xb.z, xb.w};
            float es[4] = {ev.x, ev.y, ev.z, ev.w};
            #pragma unroll
            for (int i = 0; i < 8; ++i)
                #pragma unroll
                for (int j2 = 0; j2 < 4; ++j2)
                    acc[i][j2] = fmaf(xs[i], es[j2], acc[i][j2]);
        }

        #pragma unroll
        for (int i = 0; i < 8; ++i) {
            float bv = __builtin_inff(); int bk = 0;
            #pragma unroll
            for (int j2 = 0; j2 < 4; ++j2) {
                int kg = cc * 128 + cg * 4 + j2;
                float dv = n2c[cg * 4 + j2] - 2.f * acc[i][j2];
                if (dv < bv) { bv = dv; bk = kg; }
            }
            #pragma unroll
            for (int m = 16; m >= 1; m >>= 1) {
                float ov = __shfl_xor(bv, m, 64);
                int   oi = __shfl_xor(bk, m, 64);
                if (ov < bv || (ov == bv && oi < bk)) { bv = ov; bk = oi; }
            }
            if (cg == 0) {
                int tok = tg * 8 + i;
                if (bv < runv[tok] || (bv == runv[tok] && bk < runi[tok])) {
                    runv[tok] = bv; runi[tok] = bk;
                }
            }
        }
    }
    __syncthreads();

    if (tid < 64) {
        int l = t0 + tid;
        float dsum = (l < L) ? (runv[tid] + xnorm2[tid]) : 0.f;
        #pragma unroll
        for (int m = 32; m >= 1; m >>= 1) dsum += __shfl_xor(dsum, m, 64);
        if (tid == 0) atomicAdd(diff_out, dsum * (1.f / (float)(L * DTOP)));
    }
    {
        int tok = tid >> 2, seg = tid & 3;
        int l = t0 + tok;
        if (l < L) {
            int ind = runi[tok];
            float* dst = q4 + ((size_t)b * L + l) * DTOP + seg * 16;
            const float* src = Eb + ind + (size_t)(seg * 16) * K;
            #pragma unroll
            for (int q = 0; q < 16; ++q) dst[q] = src[(size_t)q * K];
        }
    }
}

// Levels j=3..0: d=128 (input||q4), codebook cb_lvl[j][label[b]]. slot = 3-j.
__global__ __launch_bounds__(256) void vq_lvl(
    const float* __restrict__ input, const float* __restrict__ cb_lvl,
    const int* __restrict__ label, const float* __restrict__ ws,
    float* __restrict__ out)
{
    __shared__ float xT[DLVL][64];    // 32 KB
    __shared__ float Ec[64][128];     // 32 KB
    __shared__ float n2c[128];
    __shared__ float invec[128];
    __shared__ float runv[64];
    __shared__ int   runi[64];
    __shared__ float xnorm2[64];
    __shared__ float invx[64];
    __shared__ float otm[64], otz[64], otw[64];

    const int tid = threadIdx.x;
    const int tile = blockIdx.x;
    const int b = blockIdx.y;
    const int slot = blockIdx.z;
    const int j = 3 - slot;
    const bool OT = (j == 0);
    const int t0 = tile * 64;
    const int c = label[b];
    const float* Eb = cb_lvl + (size_t)(j * NCLS + c) * DLVL * K;
    const float* q4 = ws + WS_Q4;
    const float* n2 = ws + WS_N2LVL + (size_t)(j * NCLS + c) * K;
    const float* inve = ws + WS_INVE + (size_t)c * K;

    // stage x = concat(input[j], q4) transposed: 64 tokens x 32 float4
    for (int it = 0; it < 8; ++it) {
        int idx = it * 256 + tid;
        int tok = idx >> 5;
        int sg = idx & 31;
        int l = t0 + tok;
        float4 v = make_float4(0.f, 0.f, 0.f, 0.f);
        if (l < L) {
            if (sg < 16)
                v = *reinterpret_cast<const float4*>(input + ((size_t)(j * B + b) * L + l) * DTOP + sg * 4);
            else
                v = *reinterpret_cast<const float4*>(q4 + ((size_t)b * L + l) * DTOP + (sg - 16) * 4);
        }
        xT[sg * 4 + 0][tok] = v.x; xT[sg * 4 + 1][tok] = v.y;
        xT[sg * 4 + 2][tok] = v.z; xT[sg * 4 + 3][tok] = v.w;
    }
    __syncthreads();
    if (tid < 64) {
        float s = 0.f;
        for (int dd = 0; dd < DLVL; ++dd) { float v = xT[dd][tid]; s = fmaf(v, v, s); }
        xnorm2[tid] = s;
        invx[tid] = 1.f / (sqrtf(s) + 1e-8f);
        runv[tid] = __builtin_inff();
        runi[tid] = 0;
        otm[tid] = -__builtin_inff(); otz[tid] = 0.f; otw[tid] = 0.f;
    }
    const int cg = tid & 31, tg = tid >> 5;

    for (int cc = 0; cc < 4; ++cc) {
        float acc[8][4];
        #pragma unroll
        for (int i = 0; i < 8; ++i)
            #pragma unroll
            for (int j2 = 0; j2 < 4; ++j2) acc[i][j2] = 0.f;

        for (int dh = 0; dh < 2; ++dh) {
            __syncthreads();
            for (int it = 0; it < 8; ++it) {
                int idx = it * 256 + tid;
                int row = idx >> 5;
                int c4 = idx & 31;
                *reinterpret_cast<float4*>(&Ec[row][c4 * 4]) =
                    *reinterpret_cast<const float4*>(Eb + (size_t)(dh * 64 + row) * K + cc * 128 + c4 * 4);
            }
            if (dh == 0 && tid < 32) {
                *reinterpret_cast<float4*>(&n2c[tid * 4]) =
                    *reinterpret_cast<const float4*>(n2 + cc * 128 + tid * 4);
                if (OT)
                    *reinterpret_cast<float4*>(&invec[tid * 4]) =
                        *reinterpret_cast<const float4*>(inve + cc * 128 + tid * 4);
            }
            __syncthreads();

            const int dbase = dh * 64;
            for (int dd = 0; dd < 64; ++dd) {
                float4 xa = *reinterpret_cast<const float4*>(&xT[dbase + dd][tg * 8]);
                float4 xb = *reinterpret_cast<const float4*>(&xT[dbase + dd][tg * 8 + 4]);
                float4 ev = *reinterpret_cast<const float4*>(&Ec[dd][cg * 4]);
                float xs[8] = {xa.x, xa.y, xa.z, xa.w, xb.x, xb.y, xb.z, xb.w};
                float es[4] = {ev.x, ev.y, ev.z, ev.w};
                #pragma unroll
                for (int i = 0; i < 8; ++i)
                    #pragma unroll
                    for (int j2 = 0; j2 < 4; ++j2)
                        acc[i][j2] = fmaf(xs[i], es[j2], acc[i][j2]);
            }
        }

        // argmin reduction over this 128-code chunk
        #pragma unroll
        for (int i = 0; i < 8; ++i) {
            float bv = __builtin_inff(); int bk = 0;
            #pragma unroll
            for (int j2 = 0; j2 < 4; ++j2) {
                int kg = cc * 128 + cg * 4 + j2;
                float dv = n2c[cg * 4 + j2] - 2.f * acc[i][j2];
                if (dv < bv) { bv = dv; bk = kg; }
            }
            #pragma unroll
            for (int m = 16; m >= 1; m >>= 1) {
                float ov = __shfl_xor(bv, m, 64);
                int   oi = __shfl_xor(bk, m, 64);
                if (ov < bv || (ov == bv && oi < bk)) { bv = ov; bk = oi; }
            }
            if (cg == 0) {
                int tok = tg * 8 + i;
                if (bv < runv[tok] || (bv == runv[tok] && bk < runi[tok])) {
                    runv[tok] = bv; runi[tok] = bk;
                }
            }
        }

        if (OT) {
            #pragma unroll
            for (int i = 0; i < 8; ++i) {
                int tok = tg * 8 + i;
                float ivx = invx[tok];
                float m = -__builtin_inff(), z = 0.f, w = 0.f;
                #pragma unroll
                for (int j2 = 0; j2 < 4; ++j2) {
                    float s = acc[i][j2];
                    float lg = s * (1.f / 512.f);
                    float cosd = 1.f - s * ivx * invec[cg * 4 + j2];
                    float nm = fmaxf(m, lg);
                    float sc = __expf(m - nm);
                    float e  = __expf(lg - nm);
                    z = z * sc + e;
                    w = w * sc + cosd * e;
                    m = nm;
                }
                #pragma unroll
                for (int mm = 16; mm >= 1; mm >>= 1) {
                    float om = __shfl_xor(m, mm, 64);
                    float oz = __shfl_xor(z, mm, 64);
                    float ow = __shfl_xor(w, mm, 64);
                    float nm = fmaxf(m, om);
                    float s1 = __expf(m - nm), s2 = __expf(om - nm);
                    z = z * s1 + oz * s2;
                    w = w * s1 + ow * s2;
                    m = nm;
                }
                if (cg == 0) {
                    float om = otm[tok];
                    float nm = fmaxf(om, m);
                    float s1 = __expf(om - nm), s2 = __expf(m - nm);
                    otz[tok] = otz[tok] * s1 + z * s2;
                    otw[tok] = otw[tok] * s1 + w * s2;
                    otm[tok] = nm;
                }
            }
        }
    }
    __syncthreads();

    if (tid < 64) {
        int l = t0 + tid;
        float dsum = (l < L) ? (runv[tid] + xnorm2[tid]) : 0.f;
        #pragma unroll
        for (int m = 32; m >= 1; m >>= 1) dsum += __shfl_xor(dsum, m, 64);
        if (tid == 0) atomicAdd(out + DIFF_OFF, dsum * (1.f / (float)(L * DLVL)));
        if (l < L) {
            out[ID_OFF + ((size_t)slot * B + b) * L + l] = (float)runi[tid];
            if (OT) out[OT_OFF + (size_t)b * L + l] = otw[tid] / otz[tid];
        }
    }
    {
        int tok = tid >> 2, seg = tid & 3;
        int l = t0 + tok;
        if (l < L) {
            int ind = runi[tok];
            float* dst = out + (((size_t)slot * B + b) * L + l) * DLVL + seg * 32;
            const float* src = Eb + ind + (size_t)(seg * 32) * K;
            #pragma unroll
            for (int q = 0; q < 32; ++q) dst[q] = src[(size_t)q * K];
        }
    }
}

extern "C" void kernel_launch(void* const* d_in, const int* in_sizes, int n_in,
                              void* d_out, int out_size, void* d_ws, size_t ws_size,
                              hipStream_t stream) {
    const float* input  = (const float*)d_in[0];
    const float* cb_top = (const float*)d_in[1];
    const float* cb_lvl = (const float*)d_in[2];
    const int*   label  = (const int*)d_in[3];
    float* out = (float*)d_out;
    float* ws  = (float*)d_ws;

    hipMemsetAsync(out + DIFF_OFF, 0, sizeof(float), stream);

    int ncols = NCLS * K + 4 * NCLS * K;
    precompute_norms<<<(ncols + 255) / 256, 256, 0, stream>>>(cb_top, cb_lvl, ws);
    vq_top<<<dim3(4, B), 256, 0, stream>>>(input, cb_top, label, ws + WS_N2TOP,
                                           ws + WS_Q4, out + DIFF_OFF);
    vq_lvl<<<dim3(4, B, 4), 256, 0, stream>>>(input, cb_lvl, label, ws, out);
}

// Round 2
// 411.534 us; speedup vs baseline: 1.1950x; 1.1950x over previous
//
#include <hip/hip_runtime.h>
#include <hip/hip_bf16.h>
#include <math.h>

#define B 128
#define L 196
#define K 512
#define NCLS 15

// d_out layout (floats)
#define DIFF_OFF 12845056        // 4*B*L*128
#define ID_OFF   12845057
#define OT_OFF   12945409        // ID_OFF + 4*B*L

// ws layout (float indices)
#define WS_Q4    0               // B*L*64 fp32
#define WS_N2    1605632         // 75*512 fp32 (15 top mats + 60 lvl mats)
#define WS_INVE  1644032         // 15*512 fp32 (level-0 classes)
#define WS_EBT_F 1651712         // bf16 codebooks, transposed+swizzled
#define EBT_LVL_BASE 983040      // byte offset of lvl mats within EBT region

#define BAND 2.5f

typedef __attribute__((ext_vector_type(8))) short   s16x8;
typedef __attribute__((ext_vector_type(4))) float   f32x4;
typedef __attribute__((ext_vector_type(8))) unsigned short u16x8;
typedef __attribute__((ext_vector_type(4))) unsigned short u16x4;

__device__ inline unsigned short f2bf(float f) {
    __hip_bfloat16 h = __float2bfloat16(f);
    return *reinterpret_cast<unsigned short*>(&h);
}

// ---------------------------------------------------------------------------
// Precompute: per-matrix exact fp32 column norms + bf16 transposed/swizzled
// codebooks. Matrix m: m<15 -> top class m (K=64); else level j=(m-15)/15,
// class c=(m-15)%15 (K=128). EBT layout per matrix, per 64-k chunk:
//   [col(512)][slot'(8)][8 bf16]   with slot' = kslot ^ (col&7)   (128B rows)
// ---------------------------------------------------------------------------
__global__ __launch_bounds__(256) void precompute(
    const float* __restrict__ cb_top, const float* __restrict__ cb_lvl,
    float* __restrict__ ws)
{
    int bx = blockIdx.x;                 // 150 blocks
    int m = bx >> 1;
    int col = ((bx & 1) << 8) + threadIdx.x;
    bool top = (m < NCLS);
    int Kd = top ? 64 : 128;
    const float* src = top ? cb_top + (size_t)m * 64 * K
                           : cb_lvl + (size_t)(m - NCLS) * 128 * K;
    char* ebt = (char*)(ws + WS_EBT_F) +
        (top ? (size_t)m * 65536 : (size_t)EBT_LVL_BASE + (size_t)(m - NCLS) * 131072);

    float sumsq = 0.f;
    int xr = col & 7;
    for (int cc = 0; cc < Kd / 64; ++cc) {
        for (int sp = 0; sp < 8; ++sp) {
            int kb = cc * 64 + ((sp ^ xr) << 3);
            u16x8 u;
            #pragma unroll
            for (int q = 0; q < 8; ++q) {
                float e = src[(size_t)(kb + q) * K + col];
                sumsq = fmaf(e, e, sumsq);
                u[q] = f2bf(e);
            }
            *reinterpret_cast<u16x8*>(ebt + (size_t)cc * 65536 + col * 128 + sp * 16) = u;
        }
    }
    ws[WS_N2 + m * K + col] = sumsq;
    if (m >= NCLS && m < 2 * NCLS)
        ws[WS_INVE + (m - NCLS) * K + col] = 1.f / (sqrtf(sumsq) + 1e-8f);
}

// ---------------------------------------------------------------------------
// Fused VQ: bf16 MFMA GEMM (x @ E) -> approx dists -> band candidates ->
// exact fp32 rescore -> argmin/diff/quant (+ OT for level 0).
// mode 0: top (d=64, x=input[4], writes q4 to ws)
// mode 1: levels j=blockIdx.z (d=128, x=concat(input[j], q4)), slot=3-j
// Block: 512 thr = 8 waves (2 M x 4 N), tile 128M x 512N, K chunked by 64.
// ---------------------------------------------------------------------------
__global__ __launch_bounds__(512) void vq_gemm(
    const float* __restrict__ input, const float* __restrict__ cb_top,
    const float* __restrict__ cb_lvl, const int* __restrict__ label,
    float* __restrict__ ws, float* __restrict__ out, int mode)
{
    __shared__ unsigned short Et_s[512 * 64];   // 64KB: [col][slot'][8]
    __shared__ unsigned short x_s[128 * 128];   // 32KB: [row][slot'][8] (bf16)
    __shared__ float n2s[512];
    __shared__ float ivec[512];
    __shared__ float wmin[4][128];
    __shared__ float otmP[4][128], otzP[4][128], otwP[4][128];
    __shared__ float rowMin[128];
    __shared__ unsigned long long rowBest[128];
    __shared__ float xnorm_s[128];
    __shared__ float otval[128];
    __shared__ unsigned int clist[768];
    __shared__ int ccnt;
    __shared__ float dred[8];

    const int tid = threadIdx.x;
    const int tile = blockIdx.x;             // 0,1
    const int b = blockIdx.y;
    const bool isTop = (mode == 0);
    const int j = isTop ? 4 : blockIdx.z;    // level index into input_list
    const bool OT = (!isTop) && (j == 0);
    const int t0 = tile * 128;
    const int nvalid = min(L - t0, 128);     // 128 or 68
    const int c = label[b];
    const int D = isTop ? 64 : 128;
    const int XORM = isTop ? 7 : 15;

    const char* ebt = (const char*)(ws + WS_EBT_F) +
        (isTop ? (size_t)c * 65536
               : (size_t)EBT_LVL_BASE + (size_t)(j * NCLS + c) * 131072);
    const float* n2w = ws + WS_N2 + (size_t)(isTop ? c : NCLS + j * NCLS + c) * K;
    const float* q4w = ws + WS_Q4;

    // ---- init ----
    if (tid < 128) { xnorm_s[tid] = 0.f; rowBest[tid] = ~0ULL; }
    if (tid == 0) ccnt = 0;
    n2s[tid] = n2w[tid];
    if (OT) ivec[tid] = ws[WS_INVE + (size_t)c * K + tid];
    __syncthreads();

    // ---- stage x: fp32 -> bf16, swizzled; exact fp32 |x|^2 via LDS atomics ----
    {
        const int nf4 = (128 * D) >> 2;
        const int rsh = isTop ? 4 : 5;
        const int rmask = (D >> 2) - 1;
        for (int idx = tid; idx < nf4; idx += 512) {
            int row = idx >> rsh;
            int col = (idx & rmask) << 2;
            int l = t0 + row;
            float4 v = make_float4(0.f, 0.f, 0.f, 0.f);
            if (l < L) {
                if (isTop) {
                    v = *reinterpret_cast<const float4*>(
                        input + ((size_t)(4 * B + b) * L + l) * 64 + col);
                } else if (col < 64) {
                    v = *reinterpret_cast<const float4*>(
                        input + ((size_t)(j * B + b) * L + l) * 64 + col);
                } else {
                    v = *reinterpret_cast<const float4*>(
                        q4w + ((size_t)b * L + l) * 64 + (col - 64));
                }
                atomicAdd(&xnorm_s[row], v.x * v.x + v.y * v.y + v.z * v.z + v.w * v.w);
            }
            int slot = col >> 3;
            u16x4 h;
            h[0] = f2bf(v.x); h[1] = f2bf(v.y); h[2] = f2bf(v.z); h[3] = f2bf(v.w);
            *reinterpret_cast<u16x4*>(
                &x_s[row * D + ((slot ^ (row & XORM)) << 3) + (col & 7)]) = h;
        }
    }

    // ---- MFMA main loop ----
    const int wid = tid >> 6, lane = tid & 63;
    const int wM = wid >> 2, wN = wid & 3;
    const int l15 = lane & 15, l4 = lane >> 4, l7 = lane & 7;

    f32x4 acc[4][8] = {};

    const int nchunk = isTop ? 1 : 2;
    for (int cc = 0; cc < nchunk; ++cc) {
        __syncthreads();   // x staged (iter0) / prev chunk consumed
        {
            const char* src = ebt + (size_t)cc * 65536;
            char* dst = reinterpret_cast<char*>(Et_s);
            #pragma unroll
            for (int i = 0; i < 8; ++i) {
                int off = (i * 512 + tid) * 16;
                *reinterpret_cast<float4*>(dst + off) =
                    *reinterpret_cast<const float4*>(src + off);
            }
        }
        __syncthreads();
        #pragma unroll
        for (int ks = 0; ks < 2; ++ks) {
            s16x8 av[4], bv[8];
            const int slotbase = cc * 8 + ks * 4 + l4;        // x slot (k/8)
            const int kslot = ks * 4 + l4;                    // Et slot within chunk
            #pragma unroll
            for (int mi = 0; mi < 4; ++mi) {
                int row = wM * 64 + mi * 16 + l15;
                av[mi] = *reinterpret_cast<const s16x8*>(
                    &x_s[row * D + ((slotbase ^ (lane & XORM)) << 3)]);
            }
            #pragma unroll
            for (int ni = 0; ni < 8; ++ni) {
                int col = wN * 128 + ni * 16 + l15;
                bv[ni] = *reinterpret_cast<const s16x8*>(
                    &Et_s[col * 64 + ((kslot ^ l7) << 3)]);
            }
            #pragma unroll
            for (int mi = 0; mi < 4; ++mi)
                #pragma unroll
                for (int ni = 0; ni < 8; ++ni)
                    acc[mi][ni] = __builtin_amdgcn_mfma_f32_16x16x32_bf16(
                        av[mi], bv[ni], acc[mi][ni], 0, 0, 0);
        }
    }
    __syncthreads();

    // ---- E1: per-wave per-row approx-min (+ OT partials) ----
    #pragma unroll
    for (int mi = 0; mi < 4; ++mi) {
        #pragma unroll
        for (int r = 0; r < 4; ++r) {
            const int rowl = wM * 64 + mi * 16 + l4 * 4 + r;
            float bvv = 3.4e38f;
            #pragma unroll
            for (int ni = 0; ni < 8; ++ni) {
                int col = wN * 128 + ni * 16 + l15;
                float dv = n2s[col] - 2.f * acc[mi][ni][r];
                bvv = fminf(bvv, dv);
            }
            #pragma unroll
            for (int mm = 1; mm <= 8; mm <<= 1)
                bvv = fminf(bvv, __shfl_xor(bvv, mm, 64));
            if (l15 == 0) wmin[wN][rowl] = bvv;

            if (OT) {
                float ivx = 1.f / (sqrtf(xnorm_s[rowl]) + 1e-8f);
                float m_ = -3.0e38f, z_ = 0.f, w_ = 0.f;
                #pragma unroll
                for (int ni = 0; ni < 8; ++ni) {
                    int col = wN * 128 + ni * 16 + l15;
                    float s = acc[mi][ni][r];
                    float lg = s * (1.f / 512.f);
                    float cosd = 1.f - s * ivx * ivec[col];
                    float nm = fmaxf(m_, lg);
                    float sc = __expf(m_ - nm), e = __expf(lg - nm);
                    z_ = z_ * sc + e;
                    w_ = w_ * sc + cosd * e;
                    m_ = nm;
                }
                #pragma unroll
                for (int mm = 1; mm <= 8; mm <<= 1) {
                    float om = __shfl_xor(m_, mm, 64);
                    float oz = __shfl_xor(z_, mm, 64);
                    float ow = __shfl_xor(w_, mm, 64);
                    float nm = fmaxf(m_, om);
                    float s1 = __expf(m_ - nm), s2 = __expf(om - nm);
                    z_ = z_ * s1 + oz * s2;
                    w_ = w_ * s1 + ow * s2;
                    m_ = nm;
                }
                if (l15 == 0) { otmP[wN][rowl] = m_; otzP[wN][rowl] = z_; otwP[wN][rowl] = w_; }
            }
        }
    }
    __syncthreads();

    // ---- E2: combine 4 wN partials per row ----
    if (tid < 128) {
        rowMin[tid] = fminf(fminf(wmin[0][tid], wmin[1][tid]),
                            fminf(wmin[2][tid], wmin[3][tid]));
        if (OT) {
            float m_ = otmP[0][tid], z_ = otzP[0][tid], w_ = otwP[0][tid];
            #pragma unroll
            for (int q = 1; q < 4; ++q) {
                float om = otmP[q][tid], oz = otzP[q][tid], ow = otwP[q][tid];
                float nm = fmaxf(m_, om);
                float s1 = __expf(m_ - nm), s2 = __expf(om - nm);
                z_ = z_ * s1 + oz * s2;
                w_ = w_ * s1 + ow * s2;
                m_ = nm;
            }
            otval[tid] = w_ / z_;
        }
    }
    __syncthreads();

    // ---- E3: collect band candidates ----
    #pragma unroll
    for (int mi = 0; mi < 4; ++mi) {
        #pragma unroll
        for (int ni = 0; ni < 8; ++ni) {
            #pragma unroll
            for (int r = 0; r < 4; ++r) {
                int rowl = wM * 64 + mi * 16 + l4 * 4 + r;
                int col = wN * 128 + ni * 16 + l15;
                float dv = n2s[col] - 2.f * acc[mi][ni][r];
                if (rowl < nvalid && dv <= rowMin[rowl] + BAND) {
                    int pos = atomicAdd(&ccnt, 1);
                    if (pos < 768) clist[pos] = ((unsigned)rowl << 9) | (unsigned)col;
                }
            }
        }
    }
    __syncthreads();

    // ---- E4: exact fp32 rescore of candidates (16-lane groups) ----
    {
        const int ncand = min(ccnt, 768);
        const int g = tid >> 4, li = tid & 15;
        for (int e = g; e < ncand; e += 32) {
            unsigned ent = clist[e];
            int rowl = ent >> 9, col = ent & 511;
            int lgl = t0 + rowl;
            float part = 0.f;
            if (isTop) {
                if (li < 8) {
                    const float* xp = input + ((size_t)(4 * B + b) * L + lgl) * 64 + li * 8;
                    const float* ep = cb_top + ((size_t)c * 64 + li * 8) * K + col;
                    #pragma unroll
                    for (int q = 0; q < 8; ++q)
                        part = fmaf(xp[q], ep[(size_t)q * K], part);
                }
            } else {
                const float* xp = (li < 8)
                    ? input + ((size_t)(j * B + b) * L + lgl) * 64 + li * 8
                    : q4w + ((size_t)b * L + lgl) * 64 + (li - 8) * 8;
                const float* ep = cb_lvl + ((size_t)((j * NCLS + c) * 128) + li * 8) * K + col;
                #pragma unroll
                for (int q = 0; q < 8; ++q)
                    part = fmaf(xp[q], ep[(size_t)q * K], part);
            }
            #pragma unroll
            for (int mm = 1; mm <= 8; mm <<= 1)
                part += __shfl_xor(part, mm, 64);
            if (li == 0) {
                float dv = n2s[col] - 2.f * part;
                unsigned u = __float_as_uint(dv);
                u = (u & 0x80000000u) ? ~u : (u | 0x80000000u);
                unsigned long long key = ((unsigned long long)u << 32) | (unsigned)col;
                atomicMin(&rowBest[rowl], key);
            }
        }
    }
    __syncthreads();

    // ---- E5: outputs (id, ot, diff) ----
    float dc = 0.f;
    if (tid < 128 && tid < nvalid) {
        unsigned long long key = rowBest[tid];
        unsigned col = (unsigned)(key & 0xFFFFFFFFull);
        unsigned u = (unsigned)(key >> 32);
        u = (u & 0x80000000u) ? (u & 0x7FFFFFFFu) : ~u;
        float dv = __uint_as_float(u);
        dc = dv + xnorm_s[tid];
        int lgl = t0 + tid;
        if (!isTop) {
            int slot = 3 - j;
            out[ID_OFF + ((size_t)slot * B + b) * L + lgl] = (float)col;
            if (OT) out[OT_OFF + (size_t)b * L + lgl] = otval[tid];
        }
    }
    dc *= isTop ? (1.f / (L * 64.f)) : (1.f / (L * 128.f));
    #pragma unroll
    for (int mm = 1; mm <= 32; mm <<= 1) dc += __shfl_xor(dc, mm, 64);
    if (lane == 0) dred[wid] = dc;
    __syncthreads();
    if (tid == 0) atomicAdd(out + DIFF_OFF, dred[0] + dred[1]);

    // ---- gather exact fp32 codebook rows (quant / q4) ----
    {
        const int g = tid >> 4, li = tid & 15;
        for (int rowl = g; rowl < nvalid; rowl += 32) {
            unsigned col = (unsigned)(rowBest[rowl] & 0xFFFFFFFFull);
            int lgl = t0 + rowl;
            if (isTop) {
                if (li < 8) {
                    const float* ep = cb_top + ((size_t)c * 64 + li * 8) * K + col;
                    float* dst = ws + WS_Q4 + ((size_t)b * L + lgl) * 64 + li * 8;
                    #pragma unroll
                    for (int q = 0; q < 8; ++q) dst[q] = ep[(size_t)q * K];
                }
            } else {
                const float* ep = cb_lvl + ((size_t)((j * NCLS + c) * 128) + li * 8) * K + col;
                int slot = 3 - j;
                float* dst = out + (((size_t)slot * B + b) * L + lgl) * 128 + li * 8;
                #pragma unroll
                for (int q = 0; q < 8; ++q) dst[q] = ep[(size_t)q * K];
            }
        }
    }
}

extern "C" void kernel_launch(void* const* d_in, const int* in_sizes, int n_in,
                              void* d_out, int out_size, void* d_ws, size_t ws_size,
                              hipStream_t stream) {
    const float* input  = (const float*)d_in[0];
    const float* cb_top = (const float*)d_in[1];
    const float* cb_lvl = (const float*)d_in[2];
    const int*   label  = (const int*)d_in[3];
    float* out = (float*)d_out;
    float* ws  = (float*)d_ws;

    hipMemsetAsync(out + DIFF_OFF, 0, sizeof(float), stream);

    precompute<<<150, 256, 0, stream>>>(cb_top, cb_lvl, ws);
    vq_gemm<<<dim3(2, B, 1), 512, 0, stream>>>(input, cb_top, cb_lvl, label, ws, out, 0);
    vq_gemm<<<dim3(2, B, 4), 512, 0, stream>>>(input, cb_top, cb_lvl, label, ws, out, 1);
}

// Round 3
// 326.982 us; speedup vs baseline: 1.5040x; 1.2586x over previous
//
#include <hip/hip_runtime.h>
#include <hip/hip_bf16.h>
#include <math.h>

#define B 128
#define L 196
#define K 512
#define NCLS 15
#define NT 32              // tokens per block tile
#define NTILES 7           // ceil(196/32)

// d_out layout (floats)
#define DIFF_OFF 12845056  // 4*B*L*128
#define ID_OFF   12845057
#define OT_OFF   12945409  // ID_OFF + 4*B*L

// ws layout (float indices)
#define WS_Q4   0                    // B*L*64
#define WS_N2   1605632              // 75*512  ([0..14]=top, 15+j*15+c = lvl)
#define WS_INVE 1644032              // 15*512  (level-0 classes)
#define WS_CBT  1651712              // fp32 transposed codebooks [col][d]
#define CBT_LVL 491520               // float offset of lvl mats inside CBT (15*512*64)
#define WS_EBT_BYTES ((size_t)(1651712 + 4423680) * 4)   // bf16 [col][k] codebooks
#define EBT_LVL_BYTES 983040         // byte offset of lvl mats inside EBT

#define BAND 2.5f
#define CCAP 384

typedef __attribute__((ext_vector_type(8))) short s16x8;
typedef __attribute__((ext_vector_type(4))) float f32x4;
typedef __attribute__((ext_vector_type(4))) unsigned short u16x4;

__device__ inline unsigned short f2bf(float f) {
    __hip_bfloat16 h = __float2bfloat16(f);
    return *reinterpret_cast<unsigned short*>(&h);
}

// ---------------------------------------------------------------------------
// precompute: per codebook matrix (75 total) build
//   - cbT fp32 transposed [col][d]   (coalesced rescore/gather reads)
//   - EBT bf16 transposed [col][k]   (direct-from-global MFMA B fragments)
//   - exact fp32 column norms n2, and inve for level-0 classes
// block = (matrix m, 64-col tile); LDS-tiled transpose.
// ---------------------------------------------------------------------------
__global__ __launch_bounds__(256) void precompute(
    const float* __restrict__ cb_top, const float* __restrict__ cb_lvl,
    float* __restrict__ ws)
{
    __shared__ float Ld[128][65];
    __shared__ float ps[64][4];
    const int m = blockIdx.x >> 3;
    const int c0 = (blockIdx.x & 7) * 64;
    const bool top = m < NCLS;
    const int D = top ? 64 : 128;
    const float* src = top ? cb_top + (size_t)m * 64 * K
                           : cb_lvl + (size_t)(m - NCLS) * 128 * K;
    float* cbT = ws + WS_CBT + (top ? (size_t)m * K * 64
                                    : (size_t)CBT_LVL + (size_t)(m - NCLS) * K * 128);
    unsigned short* ebt = (unsigned short*)((char*)ws + WS_EBT_BYTES +
        (top ? (size_t)m * K * 64 * 2
             : (size_t)EBT_LVL_BYTES + (size_t)(m - NCLS) * K * 128 * 2));
    const int tid = threadIdx.x;

    for (int e = tid; e < D * 64; e += 256) {
        int d = e >> 6, cc = e & 63;
        Ld[d][cc] = src[(size_t)d * K + c0 + cc];
    }
    __syncthreads();

    const int col = tid >> 2, q = tid & 3;
    const int seg = D >> 2;
    float ss = 0.f;
    for (int i = 0; i < seg; ++i) {
        int d = q * seg + i;
        float v = Ld[d][col];
        ss = fmaf(v, v, ss);
        cbT[(size_t)(c0 + col) * D + d] = v;
        ebt[(size_t)(c0 + col) * D + d] = f2bf(v);
    }
    ps[col][q] = ss;
    __syncthreads();
    if (tid < 64) {
        float n2 = (ps[tid][0] + ps[tid][1]) + (ps[tid][2] + ps[tid][3]);
        ws[WS_N2 + (size_t)m * K + c0 + tid] = n2;
        if (m >= NCLS && m < 2 * NCLS)
            ws[WS_INVE + (size_t)(m - NCLS) * K + c0 + tid] = 1.f / (sqrtf(n2) + 1e-8f);
    }
}

// ---------------------------------------------------------------------------
// Fused VQ per (token-tile of 32, sample b, level): bf16 MFMA dists (B-frags
// straight from global EBT), band-candidate collect, exact fp32 rescore via
// cbT, winner gather, diff/id/OT.
// 256 thr = 4 waves; wave w owns cols w*64.. per 256-col chunk (2 chunks).
// ---------------------------------------------------------------------------
template<int D, bool IS_TOP, bool OT>
__global__ __launch_bounds__(256, 4) void vq_fused(
    const float* __restrict__ input, const int* __restrict__ label,
    float* __restrict__ ws, float* __restrict__ out, int jbase)
{
    constexpr int XS = D + 8;            // x_s row stride (shorts): +16B pad
    constexpr int NKS = D / 32;
    __shared__ unsigned short x_s[NT * XS];
    __shared__ float n2s[K];
    __shared__ float ivec[K];            // OT only
    __shared__ float xn_s[NT];
    __shared__ float wmin_s[4][NT];
    __shared__ float rowMinG[NT];
    __shared__ unsigned int clist[CCAP];
    __shared__ float clv[CCAP];
    __shared__ int ccnt;
    __shared__ unsigned long long best_s[NT];
    __shared__ float otZ[4][NT], otW[4][NT];
    __shared__ float dred[4];

    const int tid = threadIdx.x;
    const int t0 = blockIdx.x * NT;
    const int b = blockIdx.y;
    const int j = IS_TOP ? 4 : (OT ? 0 : (int)blockIdx.z + jbase);
    const int c = label[b];

    const float* xin = input + ((size_t)((IS_TOP ? 4 : j) * B + b) * L) * 64;
    const float* q4w = ws + WS_Q4 + (size_t)b * L * 64;
    const float* n2w = ws + WS_N2 + (size_t)(IS_TOP ? c : NCLS + j * NCLS + c) * K;
    const char*  ebt = (const char*)ws + WS_EBT_BYTES +
        (IS_TOP ? (size_t)c * K * 64 * 2
                : (size_t)EBT_LVL_BYTES + (size_t)(j * NCLS + c) * K * 128 * 2);
    const float* cbT = ws + WS_CBT +
        (IS_TOP ? (size_t)c * K * 64
                : (size_t)CBT_LVL + (size_t)(j * NCLS + c) * K * 128);

    // ---- init + stage x (fp32 -> bf16 into padded LDS; exact |x|^2) ----
    if (tid < NT) { xn_s[tid] = 0.f; best_s[tid] = ~0ULL; }
    if (tid == 0) ccnt = 0;
    for (int i = tid; i < K; i += 256) {
        n2s[i] = n2w[i];
        if (OT) ivec[i] = ws[WS_INVE + (size_t)c * K + i];
    }
    __syncthreads();

    for (int idx = tid; idx < NT * D / 4; idx += 256) {
        int row = idx / (D / 4);
        int k4 = (idx % (D / 4)) * 4;
        int l = t0 + row;
        float4 v = make_float4(0.f, 0.f, 0.f, 0.f);
        if (l < L) {
            const float* p = (IS_TOP || k4 < 64) ? xin + (size_t)l * 64 + k4
                                                 : q4w + (size_t)l * 64 + (k4 - 64);
            v = *reinterpret_cast<const float4*>(p);
            atomicAdd(&xn_s[row], v.x * v.x + v.y * v.y + v.z * v.z + v.w * v.w);
        }
        u16x4 h;
        h[0] = f2bf(v.x); h[1] = f2bf(v.y); h[2] = f2bf(v.z); h[3] = f2bf(v.w);
        *reinterpret_cast<u16x4*>(&x_s[row * XS + k4]) = h;
    }
    __syncthreads();

    // ---- MFMA + per-chunk epilogue ----
    const int wid = tid >> 6, lane = tid & 63;
    const int l15 = lane & 15, l4 = lane >> 4;

    float runMin[2][4];
    float zS[2][4], wS[2][4];
    #pragma unroll
    for (int mi = 0; mi < 2; ++mi)
        #pragma unroll
        for (int r = 0; r < 4; ++r) {
            runMin[mi][r] = 3.4e38f;
            if (OT) { zS[mi][r] = 0.f; wS[mi][r] = 0.f; }
        }

    for (int cc = 0; cc < 2; ++cc) {
        const int colbase = cc * 256 + wid * 64;
        f32x4 acc[2][4] = {};
        #pragma unroll
        for (int ks = 0; ks < NKS; ++ks) {
            s16x8 av[2], bv[4];
            #pragma unroll
            for (int mi = 0; mi < 2; ++mi)
                av[mi] = *reinterpret_cast<const s16x8*>(
                    &x_s[(mi * 16 + l15) * XS + ks * 32 + l4 * 8]);
            #pragma unroll
            for (int ni = 0; ni < 4; ++ni)
                bv[ni] = *reinterpret_cast<const s16x8*>(
                    ebt + ((size_t)(colbase + ni * 16 + l15) * D + ks * 32 + l4 * 8) * 2);
            #pragma unroll
            for (int mi = 0; mi < 2; ++mi)
                #pragma unroll
                for (int ni = 0; ni < 4; ++ni)
                    acc[mi][ni] = __builtin_amdgcn_mfma_f32_16x16x32_bf16(
                        av[mi], bv[ni], acc[mi][ni], 0, 0, 0);
        }
        #pragma unroll
        for (int mi = 0; mi < 2; ++mi) {
            #pragma unroll
            for (int r = 0; r < 4; ++r) {
                const int row = mi * 16 + l4 * 4 + r;
                const int lg = t0 + row;
                float dv[4];
                #pragma unroll
                for (int ni = 0; ni < 4; ++ni)
                    dv[ni] = n2s[colbase + ni * 16 + l15] - 2.f * acc[mi][ni][r];
                float mnW = fminf(fminf(dv[0], dv[1]), fminf(dv[2], dv[3]));
                #pragma unroll
                for (int s = 1; s <= 8; s <<= 1)
                    mnW = fminf(mnW, __shfl_xor(mnW, s, 64));
                runMin[mi][r] = fminf(runMin[mi][r], mnW);
                const float thr = runMin[mi][r] + BAND;
                if (lg < L) {
                    #pragma unroll
                    for (int ni = 0; ni < 4; ++ni) {
                        if (dv[ni] <= thr) {
                            int pos = atomicAdd(&ccnt, 1);
                            if (pos < CCAP) {
                                clist[pos] = ((unsigned)row << 16) |
                                             (unsigned)(colbase + ni * 16 + l15);
                                clv[pos] = dv[ni];
                            }
                        }
                    }
                }
                if (OT) {
                    float ivx = 1.f / (sqrtf(xn_s[row]) + 1e-8f);
                    #pragma unroll
                    for (int ni = 0; ni < 4; ++ni) {
                        float s = acc[mi][ni][r];
                        float e = __expf(s * (1.f / 512.f));   // |logit| tiny: no max-sub needed
                        zS[mi][r] += e;
                        wS[mi][r] += (1.f - s * ivx * ivec[colbase + ni * 16 + l15]) * e;
                    }
                }
            }
        }
    }

    // ---- wave-level partials to LDS ----
    #pragma unroll
    for (int mi = 0; mi < 2; ++mi)
        #pragma unroll
        for (int r = 0; r < 4; ++r) {
            const int row = mi * 16 + l4 * 4 + r;
            if (l15 == 0) wmin_s[wid][row] = runMin[mi][r];
            if (OT) {
                float z = zS[mi][r], w = wS[mi][r];
                #pragma unroll
                for (int s = 1; s <= 8; s <<= 1) {
                    z += __shfl_xor(z, s, 64);
                    w += __shfl_xor(w, s, 64);
                }
                if (l15 == 0) { otZ[wid][row] = z; otW[wid][row] = w; }
            }
        }
    __syncthreads();
    if (tid < NT)
        rowMinG[tid] = fminf(fminf(wmin_s[0][tid], wmin_s[1][tid]),
                             fminf(wmin_s[2][tid], wmin_s[3][tid]));
    __syncthreads();

    // ---- exact fp32 rescore of candidates (one wave per candidate) ----
    {
        const int ncand = min(ccnt, CCAP);
        for (int e = wid; e < ncand; e += 4) {
            unsigned ent = clist[e];
            int row = ent >> 16, col = ent & 0xFFFF;
            if (clv[e] > rowMinG[row] + BAND) continue;
            int l = t0 + row;
            float prod;
            if (IS_TOP) {
                prod = xin[(size_t)l * 64 + lane] * cbT[(size_t)col * 64 + lane];
            } else {
                int k = lane * 2;
                const float* xp = (k < 64) ? &xin[(size_t)l * 64 + k]
                                           : &q4w[(size_t)l * 64 + (k - 64)];
                float2 xv = *reinterpret_cast<const float2*>(xp);
                float2 ev = *reinterpret_cast<const float2*>(&cbT[(size_t)col * 128 + k]);
                prod = xv.x * ev.x + xv.y * ev.y;
            }
            #pragma unroll
            for (int s = 1; s <= 32; s <<= 1) prod += __shfl_xor(prod, s, 64);
            if (lane == 0) {
                float dvE = n2s[col] - 2.f * prod;
                unsigned u = __float_as_uint(dvE);
                u = (u & 0x80000000u) ? ~u : (u | 0x80000000u);
                atomicMin(&best_s[row], ((unsigned long long)u << 32) | (unsigned)col);
            }
        }
    }
    __syncthreads();

    // ---- finalize: gather winner row, write outputs, diff ----
    float dacc = 0.f;
    const int slot = IS_TOP ? 0 : 3 - j;
    for (int rr = wid; rr < NT; rr += 4) {
        int l = t0 + rr;
        if (l >= L) continue;
        unsigned long long key = best_s[rr];
        unsigned col = (unsigned)(key & 0xFFFFFFFFull);
        unsigned u = (unsigned)(key >> 32);
        u = (u & 0x80000000u) ? (u & 0x7FFFFFFFu) : ~u;
        float dvE = __uint_as_float(u);
        if (lane == 0) dacc += dvE + xn_s[rr];
        if (IS_TOP) {
            ws[WS_Q4 + ((size_t)b * L + l) * 64 + lane] = cbT[(size_t)col * 64 + lane];
        } else {
            int k = lane * 2;
            float2 ev = *reinterpret_cast<const float2*>(&cbT[(size_t)col * 128 + k]);
            *reinterpret_cast<float2*>(
                &out[(((size_t)slot * B + b) * L + l) * 128 + k]) = ev;
            if (lane == 0) {
                out[ID_OFF + ((size_t)slot * B + b) * L + l] = (float)col;
                if (OT) {
                    float z = (otZ[0][rr] + otZ[1][rr]) + (otZ[2][rr] + otZ[3][rr]);
                    float w = (otW[0][rr] + otW[1][rr]) + (otW[2][rr] + otW[3][rr]);
                    out[OT_OFF + (size_t)b * L + l] = w / z;
                }
            }
        }
    }
    if (lane == 0) dred[wid] = dacc;
    __syncthreads();
    if (tid == 0)
        atomicAdd(out + DIFF_OFF,
                  ((dred[0] + dred[1]) + (dred[2] + dred[3])) * (1.f / (L * (float)D)));
}

extern "C" void kernel_launch(void* const* d_in, const int* in_sizes, int n_in,
                              void* d_out, int out_size, void* d_ws, size_t ws_size,
                              hipStream_t stream) {
    const float* input  = (const float*)d_in[0];
    const float* cb_top = (const float*)d_in[1];
    const float* cb_lvl = (const float*)d_in[2];
    const int*   label  = (const int*)d_in[3];
    float* out = (float*)d_out;
    float* ws  = (float*)d_ws;

    hipMemsetAsync(out + DIFF_OFF, 0, sizeof(float), stream);

    precompute<<<600, 256, 0, stream>>>(cb_top, cb_lvl, ws);
    vq_fused<64, true, false><<<dim3(NTILES, B, 1), 256, 0, stream>>>(input, label, ws, out, 0);
    vq_fused<128, false, false><<<dim3(NTILES, B, 3), 256, 0, stream>>>(input, label, ws, out, 1);
    vq_fused<128, false, true><<<dim3(NTILES, B, 1), 256, 0, stream>>>(input, label, ws, out, 0);
}